// Round 17
// baseline (2934.348 us; speedup 1.0000x reference)
//
#include <hip/hip_runtime.h>

#define NTOT   2048
#define BATCH  32
#define TSTEPS 500
#define CAP    320               // CSR capacity/col (nnz ~ Binom(2048,0.1): max ~265)
#define RELEMS (BATCH * NTOT)    // 65536
#define OUT_BASE (TSTEPS * RELEMS)
#define GLOBI  255               // global counter slot; group g arrivals at bar[16g]

static __device__ __forceinline__ float act(float u) {
  return 1.0f / (1.0f + expf(2.0f - 3.0f * u));   // sigmoid(3u-2), round-5-validated
}
// Coherent (LLC-backed) access — producers publish through LLC (round-9-proven).
static __device__ __forceinline__ void st_coh(float* p, float v) {
  __hip_atomic_store(p, v, __ATOMIC_RELAXED, __HIP_MEMORY_SCOPE_AGENT);
}
static __device__ __forceinline__ float ld_coh(const float* p) {
  return __hip_atomic_load(p, __ATOMIC_RELAXED, __HIP_MEMORY_SCOPE_AGENT);
}

__global__ void alif_init(unsigned int* bar) { bar[threadIdx.x] = 0u; }  // 256 words

// r15-verbatim kernel body; __launch_bounds__(1024, 8) so TWO 1024-thread blocks/CU
// are legal (8 waves/EU x 4 EU = 32 waves/CU). cpb = NTOT/gridDim.x (8 or 4).
template <bool FRESH>
__global__ __launch_bounds__(1024, 8) void alif_main(
    const float* __restrict__ u0,
    const float* __restrict__ ext,
    const float* __restrict__ wrec,
    const float* __restrict__ mask,
    const float* __restrict__ sign,
    const float* __restrict__ dtv,
    float* __restrict__ rbuf,            // [nph][NTOT][BATCH] f32 (transposed r)
    float* __restrict__ usave,           // d_out (f32)
    unsigned int* __restrict__ bar) {
  const int tid  = threadIdx.x;
  const int lane = tid & 63;
  const int wv   = tid >> 6;
  const int nw   = blockDim.x >> 6;      // 16
  const int KR   = NTOT / nw;            // 128
  const int cpb  = NTOT / gridDim.x;     // 8 (256 blk) or 4 (512 blk)
  const int lcpb = (cpb == 8) ? 3 : 2;
  const int S    = 32 >> lcpb;           // slices per column: 4 or 8
  const int lS   = 5 - lcpb;

  __shared__ uint2 csr[8 * CAP];         // 20 KB (max cpb=8)
  __shared__ float red[32][32];          // 4 KB: [group][batch] partials
  __shared__ int   wcnt[16];
  __shared__ int   nnzs[8];
  __shared__ int   maxns;

  // ---- build CSR once: all waves cooperate per column (two-pass count+write) ----
  for (int clb = 0; clb < cpb; ++clb) {
    const int c = blockIdx.x * cpb + clb;
    const float* __restrict__ mrow = mask + c * NTOT;
    int cnt = 0;
    for (int k0 = wv * KR; k0 < wv * KR + KR; k0 += 64)
      cnt += __popcll(__ballot(mrow[k0 + lane] != 0.0f));
    if (lane == 0) wcnt[wv] = cnt;
    __syncthreads();
    int base = 0, total = 0;
    for (int w2 = 0; w2 < nw; ++w2) {
      if (w2 < wv) base += wcnt[w2];
      total += wcnt[w2];
    }
    for (int k0 = wv * KR; k0 < wv * KR + KR; k0 += 64) {
      const int k = k0 + lane;
      const float mv = mrow[k];
      const bool nz = (mv != 0.0f);
      const unsigned long long bal = __ballot(nz);
      if (nz) {
        const int pos = base + __popcll(bal & ((1ull << lane) - 1ull));
        const float w = mv * fmaxf(wrec[c * NTOT + k], 0.0f) * sign[k];  // exact f32
        if (pos < CAP) csr[clb * CAP + pos] = make_uint2(__float_as_uint(w), (unsigned)(k * BATCH));
      }
      base += __popcll(bal);
    }
    if (tid == 0) nnzs[clb] = (total < CAP) ? total : CAP;
    __syncthreads();                     // wcnt reuse + nnzs visibility
  }
  if (tid == 0) {
    int m = 0;
    for (int i = 0; i < cpb; ++i) m = (nnzs[i] > m) ? nnzs[i] : m;
    const int padm = 8 * S;              // Lc = maxn/S stays mult of 8
    maxns = (m + padm - 1) & ~(padm - 1);
  }
  __syncthreads();
  const int maxn = maxns;
  for (int clb = 0; clb < cpb; ++clb)    // zero-pad: fmaf(r,0,acc) exact no-op
    for (int i = nnzs[clb] + tid; i < maxn; i += blockDim.x)
      csr[clb * CAP + i] = make_uint2(0u, 0u);
  // pad-writes ordered before first use by the t=0 barrier's __syncthreads

  // ---- roles (r10): 32-thread group = (slice s, col cl); s==0 owns (b,c) state ----
  const int grp = tid >> 5;              // 0..31
  const int b   = tid & 31;
  const int cl  = grp & (cpb - 1);
  const int s   = grp >> lcpb;           // 0..S-1
  const int c   = blockIdx.x * cpb + cl;
  const bool own = (s == 0);

  float u = 0.f, dtc = 0.f, omd = 0.f;
  if (own) {
    dtc = dtv[c];
    omd = 1.0f - dtc;
    u = u0[b * NTOT + c];
    st_coh(&rbuf[c * BATCH + b], act(u));   // r_0 -> phase 0, lane-coalesced
  }
  const unsigned ngrp = gridDim.x >> 5;  // barrier groups of 32 blocks (8 or 16)
  const int g = blockIdx.x & (ngrp - 1);

  for (int t = 0; t < TSTEPS; ++t) {
    // ---- grid barrier, zero cache maintenance (round-9/10-proven) ----
    __syncthreads();                     // drains this block's stores (vmcnt 0)
    if (tid == 0) {
      const unsigned prev =
          __hip_atomic_fetch_add(&bar[16 * g], 1u, __ATOMIC_RELAXED, __HIP_MEMORY_SCOPE_AGENT);
      if (((prev + 1u) & 31u) == 0u)     // my group (32 blocks) complete for this step
        __hip_atomic_fetch_add(&bar[GLOBI], 1u, __ATOMIC_RELAXED, __HIP_MEMORY_SCOPE_AGENT);
      const unsigned gt = (unsigned)(t + 1) * ngrp;
      while (__hip_atomic_load(&bar[GLOBI], __ATOMIC_RELAXED, __HIP_MEMORY_SCOPE_AGENT) < gt)
        __builtin_amdgcn_s_sleep(1);
    }
    __syncthreads();

    // ext (owners; consumed in epilogue — hidden under the dot)
    const float e = own ? ext[(size_t)t * RELEMS + b * NTOT + c] : 0.0f;

    // ---- exact-f32 sparse dot, slice s (r10-verbatim: scalar, 8-deep MLP) ----
    const int Lc = maxn >> lS;           // mult of 8
    const uint2* __restrict__ ce = csr + cl * CAP + s * Lc;
    const size_t rph = FRESH ? (size_t)t : (size_t)(t & 1);
    const float* __restrict__ rrow = rbuf + rph * RELEMS + b;
    float a0 = 0.f, a1 = 0.f, a2 = 0.f, a3 = 0.f;
    float a4 = 0.f, a5 = 0.f, a6 = 0.f, a7 = 0.f;
    for (int i = 0; i < Lc; i += 8) {
      const uint2 e0 = ce[i],     e1 = ce[i + 1], e2 = ce[i + 2], e3 = ce[i + 3];
      const uint2 e4 = ce[i + 4], e5 = ce[i + 5], e6 = ce[i + 6], e7 = ce[i + 7];
      if (FRESH) {
        a0 = fmaf(rrow[e0.y], __uint_as_float(e0.x), a0);
        a1 = fmaf(rrow[e1.y], __uint_as_float(e1.x), a1);
        a2 = fmaf(rrow[e2.y], __uint_as_float(e2.x), a2);
        a3 = fmaf(rrow[e3.y], __uint_as_float(e3.x), a3);
        a4 = fmaf(rrow[e4.y], __uint_as_float(e4.x), a4);
        a5 = fmaf(rrow[e5.y], __uint_as_float(e5.x), a5);
        a6 = fmaf(rrow[e6.y], __uint_as_float(e6.x), a6);
        a7 = fmaf(rrow[e7.y], __uint_as_float(e7.x), a7);
      } else {
        a0 = fmaf(ld_coh(rrow + e0.y), __uint_as_float(e0.x), a0);
        a1 = fmaf(ld_coh(rrow + e1.y), __uint_as_float(e1.x), a1);
        a2 = fmaf(ld_coh(rrow + e2.y), __uint_as_float(e2.x), a2);
        a3 = fmaf(ld_coh(rrow + e3.y), __uint_as_float(e3.x), a3);
        a4 = fmaf(ld_coh(rrow + e4.y), __uint_as_float(e4.x), a4);
        a5 = fmaf(ld_coh(rrow + e5.y), __uint_as_float(e5.x), a5);
        a6 = fmaf(ld_coh(rrow + e6.y), __uint_as_float(e6.x), a6);
        a7 = fmaf(ld_coh(rrow + e7.y), __uint_as_float(e7.x), a7);
      }
    }
    red[grp][b] = (((a0 + a1) + (a2 + a3)) + ((a4 + a5) + (a6 + a7)));
    __syncthreads();

    // ---- epilogue (owners): cross-slice reduce + leaky integration (r10) ----
    if (own) {
      float rec = 0.f;
      for (int j = 0; j < S; ++j) rec += red[j * cpb + cl][b];
      u = u * omd + ((rec + 0.5f) + e) * dtc;
      const size_t wph = FRESH ? (size_t)(t + 1) : (size_t)((t + 1) & 1);
      st_coh(&rbuf[wph * RELEMS + c * BATCH + b], act(u));  // lane-coalesced publish
      usave[(size_t)t * RELEMS + b * NTOT + c] = u;         // plain store
    }
    // red[] WAR protected by next iteration's barrier __syncthreads
  }
}

// ---- outsave[t][b][o] = act(u_t) @ wout, u_t = (t==0 ? u0 : usave[t-1]) ----
__global__ __launch_bounds__(256) void alif_readout(
    const float* __restrict__ u0,
    const float* __restrict__ usave,
    const float* __restrict__ wout,
    float* __restrict__ outs) {
  const int wg = blockIdx.x * 4 + (threadIdx.x >> 6);   // 0..15999 = (t,b)
  const int lane = threadIdx.x & 63;
  const int t = wg >> 5, b = wg & 31;
  float a0 = 0.f, a1 = 0.f;
  for (int k0 = 0; k0 < NTOT; k0 += 64) {
    const int k = k0 + lane;
    const float uv = (t == 0) ? u0[b * NTOT + k] : usave[(size_t)(t - 1) * RELEMS + b * NTOT + k];
    const float r = act(uv);
    const float2 w2 = *(const float2*)(wout + k * 2);
    a0 = fmaf(r, w2.x, a0);
    a1 = fmaf(r, w2.y, a1);
  }
#pragma unroll
  for (int off = 32; off; off >>= 1) {
    a0 += __shfl_xor(a0, off, 64);
    a1 += __shfl_xor(a1, off, 64);
  }
  if (lane == 0) {
    outs[t * (BATCH * 2) + b * 2 + 0] = a0;
    outs[t * (BATCH * 2) + b * 2 + 1] = a1;
  }
}

extern "C" void kernel_launch(void* const* d_in, const int* in_sizes, int n_in,
                              void* d_out, int out_size, void* d_ws, size_t ws_size,
                              hipStream_t stream) {
  const float* u0   = (const float*)d_in[0];
  const float* ext  = (const float*)d_in[1];
  const float* wrec = (const float*)d_in[2];
  const float* mask = (const float*)d_in[3];
  const float* sign = (const float*)d_in[4];
  const float* wout = (const float*)d_in[5];
  const float* dtv  = (const float*)d_in[6];
  float* out = (float*)d_out;

  char* w = (char*)d_ws;
  unsigned int* bar  = (unsigned int*)w;                 // 1 KB (arrive 16g, global 255)
  float*        rbuf = (float*)(w + 1024);

  const size_t need = 1024 + (size_t)(TSTEPS + 1) * RELEMS * sizeof(float);  // ~125 MB
  const bool fresh = (ws_size >= need);

  alif_init<<<dim3(1), dim3(256), 0, stream>>>(bar);

  void* args[] = {(void*)&u0, (void*)&ext, (void*)&wrec, (void*)&mask, (void*)&sign,
                  (void*)&dtv, (void*)&rbuf, (void*)&out, (void*)&bar};

  const void* fn = fresh ? (const void*)alif_main<true> : (const void*)alif_main<false>;

  // 512 blocks ONLY when the occupancy API certifies 2 blocks/CU for the compiled
  // kernel (now reachable with __launch_bounds__(1024,8)); else 256 (= r15, 2.62 ms).
  // Gate-first ordering makes a non-co-resident cooperative launch impossible.
  int G = 256, nb = 0;
  hipError_t oe = fresh
      ? hipOccupancyMaxActiveBlocksPerMultiprocessor(&nb, alif_main<true>, 1024, 0)
      : hipOccupancyMaxActiveBlocksPerMultiprocessor(&nb, alif_main<false>, 1024, 0);
  if (oe == hipSuccess && nb >= 2) G = 512;

  hipError_t err = hipLaunchCooperativeKernel(fn, dim3(G), dim3(1024), args, 0, stream);
  if (err != hipSuccess && G == 512) {
    (void)hipLaunchCooperativeKernel(fn, dim3(256), dim3(1024), args, 0, stream);
  }

  alif_readout<<<dim3(TSTEPS * BATCH / 4), dim3(256), 0, stream>>>(
      u0, out, wout, out + OUT_BASE);
}

// Round 18
// 2615.726 us; speedup vs baseline: 1.1218x; 1.1218x over previous
//
#include <hip/hip_runtime.h>

#define NTOT   2048
#define BATCH  32
#define TSTEPS 500
#define CAP    320               // CSR capacity/col (nnz ~ Binom(2048,0.1): max ~265)
#define RELEMS (BATCH * NTOT)    // 65536
#define OUT_BASE (TSTEPS * RELEMS)
#define GLOBI  255               // global counter slot; group g arrivals at bar[16g]

static __device__ __forceinline__ float act(float u) {
  return 1.0f / (1.0f + expf(2.0f - 3.0f * u));   // sigmoid(3u-2), round-5-validated
}
// Coherent (LLC-backed) access — producers publish through LLC (round-9-proven).
static __device__ __forceinline__ void st_coh(float* p, float v) {
  __hip_atomic_store(p, v, __ATOMIC_RELAXED, __HIP_MEMORY_SCOPE_AGENT);
}
static __device__ __forceinline__ float ld_coh(const float* p) {
  return __hip_atomic_load(p, __ATOMIC_RELAXED, __HIP_MEMORY_SCOPE_AGENT);
}

__global__ void alif_init(unsigned int* bar) { bar[threadIdx.x] = 0u; }  // 256 words

// Measured-optimal configuration (r13/r15): 256 blocks x 1024 threads, 1 block/CU,
// 16 waves/CU; cpb = NTOT/gridDim.x = 8. FRESH rbuf -> plain cached gathers.
// NOTE (r17): 2 blocks/CU is WORSE (FETCH +33%, WRITE +60% — L2 working-set split);
// __launch_bounds__(1024,4) deliberately caps at 1 block/CU.
template <bool FRESH>
__global__ __launch_bounds__(1024, 4) void alif_main(
    const float* __restrict__ u0,
    const float* __restrict__ ext,
    const float* __restrict__ wrec,
    const float* __restrict__ mask,
    const float* __restrict__ sign,
    const float* __restrict__ dtv,
    float* __restrict__ rbuf,            // [nph][NTOT][BATCH] f32 (transposed r)
    float* __restrict__ usave,           // d_out (f32)
    unsigned int* __restrict__ bar) {
  const int tid  = threadIdx.x;
  const int lane = tid & 63;
  const int wv   = tid >> 6;
  const int nw   = blockDim.x >> 6;      // 16
  const int KR   = NTOT / nw;            // 128
  const int cpb  = NTOT / gridDim.x;     // 8 (256 blk) or 4 (512 blk)
  const int lcpb = (cpb == 8) ? 3 : 2;
  const int S    = 32 >> lcpb;           // slices per column: 4 or 8
  const int lS   = 5 - lcpb;

  __shared__ uint2 csr[8 * CAP];         // 20 KB (max cpb=8)
  __shared__ float red[32][32];          // 4 KB: [group][batch] partials
  __shared__ int   wcnt[16];
  __shared__ int   nnzs[8];
  __shared__ int   maxns;

  // ---- build CSR once: all waves cooperate per column (two-pass count+write) ----
  for (int clb = 0; clb < cpb; ++clb) {
    const int c = blockIdx.x * cpb + clb;
    const float* __restrict__ mrow = mask + c * NTOT;
    int cnt = 0;
    for (int k0 = wv * KR; k0 < wv * KR + KR; k0 += 64)
      cnt += __popcll(__ballot(mrow[k0 + lane] != 0.0f));
    if (lane == 0) wcnt[wv] = cnt;
    __syncthreads();
    int base = 0, total = 0;
    for (int w2 = 0; w2 < nw; ++w2) {
      if (w2 < wv) base += wcnt[w2];
      total += wcnt[w2];
    }
    for (int k0 = wv * KR; k0 < wv * KR + KR; k0 += 64) {
      const int k = k0 + lane;
      const float mv = mrow[k];
      const bool nz = (mv != 0.0f);
      const unsigned long long bal = __ballot(nz);
      if (nz) {
        const int pos = base + __popcll(bal & ((1ull << lane) - 1ull));
        const float w = mv * fmaxf(wrec[c * NTOT + k], 0.0f) * sign[k];  // exact f32
        if (pos < CAP) csr[clb * CAP + pos] = make_uint2(__float_as_uint(w), (unsigned)(k * BATCH));
      }
      base += __popcll(bal);
    }
    if (tid == 0) nnzs[clb] = (total < CAP) ? total : CAP;
    __syncthreads();                     // wcnt reuse + nnzs visibility
  }
  if (tid == 0) {
    int m = 0;
    for (int i = 0; i < cpb; ++i) m = (nnzs[i] > m) ? nnzs[i] : m;
    const int padm = 8 * S;              // Lc = maxn/S stays mult of 8
    maxns = (m + padm - 1) & ~(padm - 1);
  }
  __syncthreads();
  const int maxn = maxns;
  for (int clb = 0; clb < cpb; ++clb)    // zero-pad: fmaf(r,0,acc) exact no-op
    for (int i = nnzs[clb] + tid; i < maxn; i += blockDim.x)
      csr[clb * CAP + i] = make_uint2(0u, 0u);
  // pad-writes ordered before first use by the t=0 barrier's __syncthreads

  // ---- roles (r10): 32-thread group = (slice s, col cl); s==0 owns (b,c) state ----
  const int grp = tid >> 5;              // 0..31
  const int b   = tid & 31;
  const int cl  = grp & (cpb - 1);
  const int s   = grp >> lcpb;           // 0..S-1
  const int c   = blockIdx.x * cpb + cl;
  const bool own = (s == 0);

  float u = 0.f, dtc = 0.f, omd = 0.f;
  if (own) {
    dtc = dtv[c];
    omd = 1.0f - dtc;
    u = u0[b * NTOT + c];
    st_coh(&rbuf[c * BATCH + b], act(u));   // r_0 -> phase 0, lane-coalesced
  }
  const unsigned ngrp = gridDim.x >> 5;  // barrier groups of 32 blocks (8 or 16)
  const int g = blockIdx.x & (ngrp - 1);

  for (int t = 0; t < TSTEPS; ++t) {
    // ---- grid barrier, zero cache maintenance (round-9/10-proven) ----
    __syncthreads();                     // drains this block's stores (vmcnt 0)
    if (tid == 0) {
      const unsigned prev =
          __hip_atomic_fetch_add(&bar[16 * g], 1u, __ATOMIC_RELAXED, __HIP_MEMORY_SCOPE_AGENT);
      if (((prev + 1u) & 31u) == 0u)     // my group (32 blocks) complete for this step
        __hip_atomic_fetch_add(&bar[GLOBI], 1u, __ATOMIC_RELAXED, __HIP_MEMORY_SCOPE_AGENT);
      const unsigned gt = (unsigned)(t + 1) * ngrp;
      while (__hip_atomic_load(&bar[GLOBI], __ATOMIC_RELAXED, __HIP_MEMORY_SCOPE_AGENT) < gt)
        __builtin_amdgcn_s_sleep(1);
    }
    __syncthreads();

    // ext (owners; consumed in epilogue — hidden under the dot)
    const float e = own ? ext[(size_t)t * RELEMS + b * NTOT + c] : 0.0f;

    // ---- exact-f32 sparse dot, slice s (r10-verbatim: scalar, 8-deep MLP) ----
    const int Lc = maxn >> lS;           // mult of 8
    const uint2* __restrict__ ce = csr + cl * CAP + s * Lc;
    const size_t rph = FRESH ? (size_t)t : (size_t)(t & 1);
    const float* __restrict__ rrow = rbuf + rph * RELEMS + b;
    float a0 = 0.f, a1 = 0.f, a2 = 0.f, a3 = 0.f;
    float a4 = 0.f, a5 = 0.f, a6 = 0.f, a7 = 0.f;
    for (int i = 0; i < Lc; i += 8) {
      const uint2 e0 = ce[i],     e1 = ce[i + 1], e2 = ce[i + 2], e3 = ce[i + 3];
      const uint2 e4 = ce[i + 4], e5 = ce[i + 5], e6 = ce[i + 6], e7 = ce[i + 7];
      if (FRESH) {
        a0 = fmaf(rrow[e0.y], __uint_as_float(e0.x), a0);
        a1 = fmaf(rrow[e1.y], __uint_as_float(e1.x), a1);
        a2 = fmaf(rrow[e2.y], __uint_as_float(e2.x), a2);
        a3 = fmaf(rrow[e3.y], __uint_as_float(e3.x), a3);
        a4 = fmaf(rrow[e4.y], __uint_as_float(e4.x), a4);
        a5 = fmaf(rrow[e5.y], __uint_as_float(e5.x), a5);
        a6 = fmaf(rrow[e6.y], __uint_as_float(e6.x), a6);
        a7 = fmaf(rrow[e7.y], __uint_as_float(e7.x), a7);
      } else {
        a0 = fmaf(ld_coh(rrow + e0.y), __uint_as_float(e0.x), a0);
        a1 = fmaf(ld_coh(rrow + e1.y), __uint_as_float(e1.x), a1);
        a2 = fmaf(ld_coh(rrow + e2.y), __uint_as_float(e2.x), a2);
        a3 = fmaf(ld_coh(rrow + e3.y), __uint_as_float(e3.x), a3);
        a4 = fmaf(ld_coh(rrow + e4.y), __uint_as_float(e4.x), a4);
        a5 = fmaf(ld_coh(rrow + e5.y), __uint_as_float(e5.x), a5);
        a6 = fmaf(ld_coh(rrow + e6.y), __uint_as_float(e6.x), a6);
        a7 = fmaf(ld_coh(rrow + e7.y), __uint_as_float(e7.x), a7);
      }
    }
    red[grp][b] = (((a0 + a1) + (a2 + a3)) + ((a4 + a5) + (a6 + a7)));
    __syncthreads();

    // ---- epilogue (owners): cross-slice reduce + leaky integration (r10) ----
    if (own) {
      float rec = 0.f;
      for (int j = 0; j < S; ++j) rec += red[j * cpb + cl][b];
      u = u * omd + ((rec + 0.5f) + e) * dtc;
      const size_t wph = FRESH ? (size_t)(t + 1) : (size_t)((t + 1) & 1);
      st_coh(&rbuf[wph * RELEMS + c * BATCH + b], act(u));  // lane-coalesced publish
      usave[(size_t)t * RELEMS + b * NTOT + c] = u;         // plain store
    }
    // red[] WAR protected by next iteration's barrier __syncthreads
  }
}

// ---- outsave[t][b][o] = act(u_t) @ wout, u_t = (t==0 ? u0 : usave[t-1]) ----
__global__ __launch_bounds__(256) void alif_readout(
    const float* __restrict__ u0,
    const float* __restrict__ usave,
    const float* __restrict__ wout,
    float* __restrict__ outs) {
  const int wg = blockIdx.x * 4 + (threadIdx.x >> 6);   // 0..15999 = (t,b)
  const int lane = threadIdx.x & 63;
  const int t = wg >> 5, b = wg & 31;
  float a0 = 0.f, a1 = 0.f;
  for (int k0 = 0; k0 < NTOT; k0 += 64) {
    const int k = k0 + lane;
    const float uv = (t == 0) ? u0[b * NTOT + k] : usave[(size_t)(t - 1) * RELEMS + b * NTOT + k];
    const float r = act(uv);
    const float2 w2 = *(const float2*)(wout + k * 2);
    a0 = fmaf(r, w2.x, a0);
    a1 = fmaf(r, w2.y, a1);
  }
#pragma unroll
  for (int off = 32; off; off >>= 1) {
    a0 += __shfl_xor(a0, off, 64);
    a1 += __shfl_xor(a1, off, 64);
  }
  if (lane == 0) {
    outs[t * (BATCH * 2) + b * 2 + 0] = a0;
    outs[t * (BATCH * 2) + b * 2 + 1] = a1;
  }
}

extern "C" void kernel_launch(void* const* d_in, const int* in_sizes, int n_in,
                              void* d_out, int out_size, void* d_ws, size_t ws_size,
                              hipStream_t stream) {
  const float* u0   = (const float*)d_in[0];
  const float* ext  = (const float*)d_in[1];
  const float* wrec = (const float*)d_in[2];
  const float* mask = (const float*)d_in[3];
  const float* sign = (const float*)d_in[4];
  const float* wout = (const float*)d_in[5];
  const float* dtv  = (const float*)d_in[6];
  float* out = (float*)d_out;

  char* w = (char*)d_ws;
  unsigned int* bar  = (unsigned int*)w;                 // 1 KB (arrive 16g, global 255)
  float*        rbuf = (float*)(w + 1024);

  const size_t need = 1024 + (size_t)(TSTEPS + 1) * RELEMS * sizeof(float);  // ~125 MB
  const bool fresh = (ws_size >= need);

  alif_init<<<dim3(1), dim3(256), 0, stream>>>(bar);

  void* args[] = {(void*)&u0, (void*)&ext, (void*)&wrec, (void*)&mask, (void*)&sign,
                  (void*)&dtv, (void*)&rbuf, (void*)&out, (void*)&bar};

  const void* fn = fresh ? (const void*)alif_main<true> : (const void*)alif_main<false>;

  // Measured optimum: 256 blocks (1/CU). r17 proved 2 blocks/CU regresses (L2 split).
  // The occupancy gate keeps a certified fallback path but at launch_bounds(1024,4)
  // nb==1, so G stays 256 by construction.
  int G = 256, nb = 0;
  hipError_t oe = fresh
      ? hipOccupancyMaxActiveBlocksPerMultiprocessor(&nb, alif_main<true>, 1024, 0)
      : hipOccupancyMaxActiveBlocksPerMultiprocessor(&nb, alif_main<false>, 1024, 0);
  (void)oe; (void)nb;                                    // intentionally pinned to 256

  hipError_t err = hipLaunchCooperativeKernel(fn, dim3(G), dim3(1024), args, 0, stream);
  if (err != hipSuccess) {
    (void)hipLaunchCooperativeKernel(fn, dim3(G), dim3(1024), args, 0, stream);
  }

  alif_readout<<<dim3(TSTEPS * BATCH / 4), dim3(256), 0, stream>>>(
      u0, out, wout, out + OUT_BASE);
}